// Round 6
// baseline (442.856 us; speedup 1.0000x reference)
//
#include <hip/hip_runtime.h>
#include <hip/hip_bf16.h>

// ---------------------------------------------------------------------------
// GraphConv (DGL, norm='both', relu) x2, aggregate-first:
//   out = relu( (D_in^-1/2 A D_out^-1/2 X) @ W + b )
// Pipeline:
//   memset : 4 bucket-cursor arrays (4KB)
//   wprep  : W -> bf16 W^T chunk-tiled + XOR-swizzled global image
//   part   : edges -> 196 coarse buckets, 4 channels (c/d x dst/src),
//            in-LDS chunk sort + run-coalesced flush (write-combined)
//   b2s    : per src-bucket 256-bin LDS count -> out-degree
//   cast   : Xb = bf16(X * rsqrt(outdeg))
//   b2d    : per dst-bucket LDS sort -> linear CSR + rs/deg
//   fused  : per block: 8 waves gather 32 nodes -> bf16 LDS a-tile
//            -> MFMA with pre-swizzled W (global_load_lds) -> bias+relu
//            -> d_out.  (GEMM fused into aggregation; no A round-trip.)
// ---------------------------------------------------------------------------

typedef __attribute__((ext_vector_type(8))) short short8;
typedef __attribute__((ext_vector_type(4))) float f32x4;

#define RND 4096      // edges per partition chunk
#define CAPMAX 8960   // max bucket capacity (LDS sort limit)

static __device__ __forceinline__ ushort f2b(float f) {
    __hip_bfloat16 h = __float2bfloat16(f);
    return *reinterpret_cast<ushort*>(&h);
}
static __device__ __forceinline__ float b2f(ushort u) {
    union { unsigned int i; float f; } c;
    c.i = ((unsigned int)u) << 16;
    return c.f;
}
static __device__ __forceinline__ void gld_lds16(const void* g, void* l) {
    __builtin_amdgcn_global_load_lds(
        (const __attribute__((address_space(1))) unsigned int*)g,
        (__attribute__((address_space(3))) unsigned int*)l, 16, 0, 0);
}

// ---------------- part: 4-channel chunk partition with WC flush ------------
__global__ __launch_bounds__(256) void part_kernel(
    const int* __restrict__ src_c, const int* __restrict__ dst_c, int Ec, int Rc,
    const int* __restrict__ src_d, const int* __restrict__ dst_d, int Ed, int Rd,
    int* gf_cd, int* gf_cs, int* gf_dd, int* gf_ds,
    int* dbuf_c, int* sbuf_c, int* dbuf_d, int* sbuf_d, int capc, int capd)
{
    __shared__ int pk[RND];
    __shared__ unsigned char pb[RND];
    __shared__ int hist[256], st[256], ex2[256], cur[256], gbase[256];

    const int tid = threadIdx.x;
    const int bid = blockIdx.x;
    const int* keys; const int* pays; int E; int* gf; int* buf; int cap; int e0;
    if (bid < Rc)            { keys = dst_c; pays = src_c; E = Ec; gf = gf_cd; buf = dbuf_c; cap = capc; e0 = bid * RND; }
    else if (bid < 2 * Rc)   { keys = src_c; pays = 0;     E = Ec; gf = gf_cs; buf = sbuf_c; cap = capc; e0 = (bid - Rc) * RND; }
    else if (bid < 2 * Rc + Rd) { keys = dst_d; pays = src_d; E = Ed; gf = gf_dd; buf = dbuf_d; cap = capd; e0 = (bid - 2 * Rc) * RND; }
    else                     { keys = src_d; pays = 0;     E = Ed; gf = gf_ds; buf = sbuf_d; cap = capd; e0 = (bid - 2 * Rc - Rd) * RND; }

    hist[tid] = 0;
    __syncthreads();

    int kb[RND / 256], pv[RND / 256];
    int n = 0;
#pragma unroll
    for (int r = 0; r < RND / 256; ++r) {
        int e = e0 + r * 256 + tid;
        if (e < E) {
            int k = keys[e];
            pv[r] = pays ? ((pays[e] << 8) | (k & 255)) : k;
            kb[r] = k >> 8;
            atomicAdd(&hist[kb[r]], 1);
            n = r + 1;
        }
    }
    __syncthreads();

    int x = hist[tid];
    st[tid] = x;
    __syncthreads();
    for (int off = 1; off < 256; off <<= 1) {
        int t2 = 0;
        if (tid >= off) t2 = st[tid - off];
        __syncthreads();
        if (tid >= off) st[tid] += t2;
        __syncthreads();
    }
    ex2[tid] = st[tid] - x;
    cur[tid] = st[tid] - x;
    __syncthreads();

    for (int r = 0; r < n; ++r) {
        int slot = atomicAdd(&cur[kb[r]], 1);
        pk[slot] = pv[r];
        pb[slot] = (unsigned char)kb[r];
    }
    if (x) gbase[tid] = atomicAdd(&gf[tid], x);
    __syncthreads();

    int m = st[255];
    for (int i = tid; i < m; i += 256) {
        int b = pb[i];
        int pos = gbase[b] + (i - ex2[b]);
        if (pos < cap) buf[(size_t)b * cap + pos] = pk[i];
    }
}

// ---------------- b2s: per src-bucket count -> out-degree ------------------
__global__ __launch_bounds__(256) void b2s_kernel(
    const int* __restrict__ sbuf_c, const int* __restrict__ gf_cs, int capc, int* cnt_c,
    const int* __restrict__ sbuf_d, const int* __restrict__ gf_ds, int capd, int* cnt_d,
    int N, int NBKT)
{
    __shared__ int h[256];
    const int tid = threadIdx.x;
    const int* sbuf; const int* gf; int cap; int* cnt; int bb;
    if ((int)blockIdx.x < NBKT) { sbuf = sbuf_c; gf = gf_cs; cap = capc; cnt = cnt_c; bb = blockIdx.x; }
    else { sbuf = sbuf_d; gf = gf_ds; cap = capd; cnt = cnt_d; bb = blockIdx.x - NBKT; }
    h[tid] = 0;
    __syncthreads();
    int m = gf[bb]; if (m > cap) m = cap;
    const int* reg = sbuf + (size_t)bb * cap;
    for (int i = tid; i < m; i += 256) atomicAdd(&h[reg[i] & 255], 1);
    __syncthreads();
    int v = bb * 256 + tid;
    if (v < N) cnt[v] = h[tid];
}

// ---------------- b2d: per dst-bucket LDS sort -> linear CSR + rs/deg ------
__global__ __launch_bounds__(256) void b2d_kernel(
    int* dbuf_c, const int* __restrict__ gf_cd, int capc, int* rs_c, int* dg_c,
    int* dbuf_d, const int* __restrict__ gf_dd, int capd, int* rs_d, int* dg_d,
    int N, int NBKT)
{
    __shared__ int pk[CAPMAX];
    __shared__ int h[256], st[256], ex2[256], cur[256];
    const int tid = threadIdx.x;
    int* bbuf; const int* gf; int cap; int* rs; int* dg; int bb;
    if ((int)blockIdx.x < NBKT) { bbuf = dbuf_c; gf = gf_cd; cap = capc; rs = rs_c; dg = dg_c; bb = blockIdx.x; }
    else { bbuf = dbuf_d; gf = gf_dd; cap = capd; rs = rs_d; dg = dg_d; bb = blockIdx.x - NBKT; }

    int m = gf[bb]; if (m > cap) m = cap;
    int* reg = bbuf + (size_t)bb * cap;

    h[tid] = 0;
    __syncthreads();
    for (int i = tid; i < m; i += 256) atomicAdd(&h[reg[i] & 255], 1);
    __syncthreads();
    int x = h[tid];
    st[tid] = x;
    __syncthreads();
    for (int off = 1; off < 256; off <<= 1) {
        int t2 = 0;
        if (tid >= off) t2 = st[tid - off];
        __syncthreads();
        if (tid >= off) st[tid] += t2;
        __syncthreads();
    }
    int ex_t = st[tid] - x;
    ex2[tid] = ex_t;
    cur[tid] = ex_t;
    int v = bb * 256 + tid;
    if (v < N) { rs[v] = bb * cap + ex_t; dg[v] = x; }
    __syncthreads();
    for (int i = tid; i < m; i += 256) {
        int p = reg[i];
        int slot = atomicAdd(&cur[p & 255], 1);
        pk[slot] = p >> 8;
    }
    __syncthreads();
    for (int i = tid; i < m; i += 256) reg[i] = pk[i];
}

// ---------------- W prep: bf16 W^T chunk-tiled + swizzled image ------------
__global__ __launch_bounds__(256) void wprep_kernel(
    const float* __restrict__ Wc, const float* __restrict__ Wd,
    ushort* __restrict__ Wtc, ushort* __restrict__ Wtd)
{
    int t = blockIdx.x * 256 + threadIdx.x;
    ushort o[8];
    if (t < 2048) {            // c: K=BN=BK=128: 128 n x 16 slots
        int n = t >> 4, slot = t & 15;
        int k0 = (slot ^ (n & 7)) << 3;
#pragma unroll
        for (int j = 0; j < 8; ++j) o[j] = f2b(Wc[(k0 + j) * 128 + n]);
        uint4 vv;
        vv.x = (unsigned)o[0] | ((unsigned)o[1] << 16);
        vv.y = (unsigned)o[2] | ((unsigned)o[3] << 16);
        vv.z = (unsigned)o[4] | ((unsigned)o[5] << 16);
        vv.w = (unsigned)o[6] | ((unsigned)o[7] << 16);
        *(uint4*)&Wtc[n * 128 + slot * 8] = vv;
    } else if (t < 2048 + 8192) {  // d: K=BN=256, BK=64: 4 chunks x 256 n x 8 slots
        int tt = t - 2048;
        int ci = tt >> 11, r = tt & 2047;
        int n = r >> 3, slot = r & 7;
        int k0 = ci * 64 + ((slot ^ (n & 7)) << 3);
#pragma unroll
        for (int j = 0; j < 8; ++j) o[j] = f2b(Wd[(k0 + j) * 256 + n]);
        uint4 vv;
        vv.x = (unsigned)o[0] | ((unsigned)o[1] << 16);
        vv.y = (unsigned)o[2] | ((unsigned)o[3] << 16);
        vv.z = (unsigned)o[4] | ((unsigned)o[5] << 16);
        vv.w = (unsigned)o[6] | ((unsigned)o[7] << 16);
        *(uint4*)&Wtd[ci * 16384 + n * 64 + slot * 8] = vv;
    }
}

// ---------------- cast + out-norm scale to bf16 ----------------------------
__global__ __launch_bounds__(256) void cast_kernel(
    const float* __restrict__ Xc, const int* __restrict__ coc, ushort* __restrict__ Xbc,
    const float* __restrict__ Xd, const int* __restrict__ cod, ushort* __restrict__ Xbd,
    int N, int nbc)
{
    const float* X; const int* co; ushort* Xb; int C4, t;
    if ((int)blockIdx.x < nbc) { X = Xc; co = coc; Xb = Xbc; C4 = 32; t = blockIdx.x * 256 + threadIdx.x; }
    else { X = Xd; co = cod; Xb = Xbd; C4 = 64; t = (blockIdx.x - nbc) * 256 + threadIdx.x; }
    if (t >= N * C4) return;
    int row = t / C4, c4 = t % C4;
    int od = co[row]; if (od < 1) od = 1;
    float nr = rsqrtf((float)od);
    float4 xv = ((const float4*)(X + (size_t)row * (C4 * 4)))[c4];
    ushort4 o;
    o.x = f2b(xv.x * nr); o.y = f2b(xv.y * nr);
    o.z = f2b(xv.z * nr); o.w = f2b(xv.w * nr);
    ((ushort4*)(Xb + (size_t)row * (C4 * 4)))[c4] = o;
}

// ---------------- fused gather + MFMA GEMM + bias + relu -------------------
// Block: 512 threads (8 waves). 32 dst nodes. Gather -> bf16 swizzled LDS
// a-tile; W image (pre-swizzled, chunked) staged via global_load_lds;
// MFMA 16x16x32; epilogue bias+relu to d_out.
template <int VEC>   // 2: D=128 (graph c), 4: D=256 (graph d)
static __device__ __forceinline__ void fused_branch(
    int blk, const ushort* __restrict__ Xb, const int* __restrict__ rs,
    const int* __restrict__ dg, const int* __restrict__ csr,
    const ushort* __restrict__ Wt, const float* __restrict__ bias,
    float* __restrict__ out, int N, ushort* At, ushort* Wls)
{
    constexpr int D = VEC * 64;
    constexpr int NCH = (D * D) / 16384;   // 32KB bf16 chunks: c=1, d=4
    constexpr int BK = D / NCH;            // 128 / 64
    constexpr int NC = D / 64;             // 16-col frags per wave: 2 / 4
    const int tid = threadIdx.x;
    const int lane = tid & 63, wid = tid >> 6;

    // stage W chunk 0 early — hides under gather latency
#pragma unroll
    for (int it = 0; it < 4; ++it) {
        int off16 = it * 512 + tid;
        gld_lds16(&Wt[off16 * 8], &Wls[off16 * 8]);
    }

    // ---- gather: 8 waves x 4 nodes ----
    const int node0 = blk * 32;
#pragma unroll
    for (int s = 0; s < 4; ++s) {
        const int row = wid * 4 + s;
        const int v = node0 + row;
        float acc[VEC];
#pragma unroll
        for (int k = 0; k < VEC; ++k) acc[k] = 0.f;
        int deg = 0;
        if (v < N) {
            deg = dg[v];
            const int* rowp = csr + rs[v];
            for (int base = 0; base < deg; base += 64) {
                int m = deg - base; if (m > 64) m = 64;
                int u_l = (lane < m) ? rowp[base + lane] : 0;
#pragma unroll 8
                for (int j = 0; j < m; ++j) {
                    int u = __shfl(u_l, j);
                    const ushort* xr = Xb + (size_t)u * D + lane * VEC;
                    if constexpr (VEC == 2) {
                        unsigned int xv = *(const unsigned int*)xr;
                        acc[0] += b2f((ushort)(xv & 0xffff));
                        acc[1] += b2f((ushort)(xv >> 16));
                    } else {
                        uint2 xv = *(const uint2*)xr;
                        acc[0] += b2f((ushort)(xv.x & 0xffff));
                        acc[1] += b2f((ushort)(xv.x >> 16));
                        acc[2] += b2f((ushort)(xv.y & 0xffff));
                        acc[3] += b2f((ushort)(xv.y >> 16));
                    }
                }
            }
        }
        // emit bf16 row (zeros for v>=N), XOR-swizzled slot layout
        float nd = rsqrtf((float)(deg < 1 ? 1 : deg));
        const int k0 = lane * VEC;
        const int slot = (k0 >> 3) ^ (row & 7);
        ushort* dstp = &At[row * D + slot * 8 + (k0 & 7)];
        if constexpr (VEC == 2) {
            unsigned int pk = (unsigned)f2b(acc[0] * nd) | ((unsigned)f2b(acc[1] * nd) << 16);
            *(unsigned int*)dstp = pk;
        } else {
            uint2 pk;
            pk.x = (unsigned)f2b(acc[0] * nd) | ((unsigned)f2b(acc[1] * nd) << 16);
            pk.y = (unsigned)f2b(acc[2] * nd) | ((unsigned)f2b(acc[3] * nd) << 16);
            *(uint2*)dstp = pk;
        }
    }
    __syncthreads();   // a-tile ready; W chunk 0 drained (vmcnt before barrier)

    // ---- MFMA: waves 2(row-tiles) x 4(col-groups) ----
    const int wr = wid >> 2, wc = wid & 3;
    const int lr = lane & 15, lk8 = (lane >> 4) * 8;
    f32x4 acc[NC];
#pragma unroll
    for (int nc = 0; nc < NC; ++nc) acc[nc] = (f32x4)0.f;

#pragma unroll
    for (int ci = 0; ci < NCH; ++ci) {
        if (ci) {
            __syncthreads();   // prior MFMA reads of Wls done
#pragma unroll
            for (int it = 0; it < 4; ++it) {
                int off16 = it * 512 + tid;
                gld_lds16(&Wt[ci * 16384 + off16 * 8], &Wls[off16 * 8]);
            }
            __syncthreads();
        }
#pragma unroll
        for (int k0 = 0; k0 < BK; k0 += 32) {
            const int r = wr * 16 + lr;
            const int kg = ci * BK + k0 + lk8;
            const int aslot = (kg >> 3) ^ (r & 7);
            short8 a = *(const short8*)&At[r * D + aslot * 8];
#pragma unroll
            for (int nc = 0; nc < NC; ++nc) {
                const int n = wc * (NC * 16) + nc * 16 + lr;
                const int kk = k0 + lk8;
                const int bslot = (kk >> 3) ^ (n & 7);
                short8 b = *(const short8*)&Wls[n * BK + bslot * 8];
                acc[nc] = __builtin_amdgcn_mfma_f32_16x16x32_bf16(a, b, acc[nc], 0, 0, 0);
            }
        }
    }

    // epilogue: bias + relu (C/D: col=lane&15, row=(lane>>4)*4+reg)
#pragma unroll
    for (int nc = 0; nc < NC; ++nc) {
        const int col = wc * (NC * 16) + nc * 16 + lr;
        const float bv = bias[col];
#pragma unroll
        for (int r4 = 0; r4 < 4; ++r4) {
            const int row = wr * 16 + (lane >> 4) * 4 + r4;
            const int v = node0 + row;
            if (v < N)
                out[(size_t)v * D + col] = fmaxf(acc[nc][r4] + bv, 0.f);
        }
    }
}

__global__ __launch_bounds__(512) void fused_kernel(
    const ushort* __restrict__ Xbc, const int* __restrict__ rsc,
    const int* __restrict__ dgc, const int* __restrict__ csrc,
    const ushort* __restrict__ Wtc, const float* __restrict__ bc, float* outc,
    const ushort* __restrict__ Xbd, const int* __restrict__ rsd,
    const int* __restrict__ dgd, const int* __restrict__ csrd,
    const ushort* __restrict__ Wtd, const float* __restrict__ bd, float* outd,
    int N, int nblkc)
{
    __shared__ ushort At[32 * 256];   // 16 KB (c uses first 8 KB)
    __shared__ ushort Wls[16384];     // 32 KB W chunk
    if ((int)blockIdx.x < nblkc)
        fused_branch<2>(blockIdx.x, Xbc, rsc, dgc, csrc, Wtc, bc, outc, N, At, Wls);
    else
        fused_branch<4>(blockIdx.x - nblkc, Xbd, rsd, dgd, csrd, Wtd, bd, outd, N, At, Wls);
}

// ---------------------------------------------------------------------------
extern "C" void kernel_launch(void* const* d_in, const int* in_sizes, int n_in,
                              void* d_out, int out_size, void* d_ws, size_t ws_size,
                              hipStream_t stream)
{
    const float* feat_c = (const float*)d_in[0];
    const float* feat_d = (const float*)d_in[1];
    const int* src_c = (const int*)d_in[2];
    const int* dst_c = (const int*)d_in[3];
    const int* src_d = (const int*)d_in[4];
    const int* dst_d = (const int*)d_in[5];
    const float* W_c = (const float*)d_in[6];
    const float* b_c = (const float*)d_in[7];
    const float* W_d = (const float*)d_in[8];
    const float* b_d = (const float*)d_in[9];

    const int D_c = in_sizes[7];          // 128
    const int D_d = in_sizes[9];          // 256
    const int N = in_sizes[0] / D_c;      // 50000
    const int E_c = in_sizes[2];
    const int E_d = in_sizes[4];

    float* out_c = (float*)d_out;
    float* out_d = (float*)d_out + (size_t)N * D_c;

    const int NBKT = (N + 255) >> 8;      // 196
    int capc = E_c / NBKT; capc += 8 * (int)sqrtf((float)capc) + 32; capc = (capc + 15) & ~15;
    int capd = E_d / NBKT; capd += 8 * (int)sqrtf((float)capd) + 32; capd = (capd + 15) & ~15;
    if (capc > CAPMAX) capc = CAPMAX;
    if (capd > CAPMAX) capd = CAPMAX;

    // workspace layout (ints unless noted)
    int* ws = (int*)d_ws;
    int* cnt_out_c = ws;                          // N
    int* cnt_out_d = ws + N;                      // N
    int* gf_cd = ws + 2 * (size_t)N;              // 256
    int* gf_cs = gf_cd + 256;                     // 256
    int* gf_dd = gf_cs + 256;                     // 256
    int* gf_ds = gf_dd + 256;                     // 256
    int* rs_c  = gf_ds + 256;                     // N
    int* dg_c  = rs_c + N;                        // N
    int* rs_d  = dg_c + N;                        // N
    int* dg_d  = rs_d + N;                        // N
    ushort* Wt_c = (ushort*)(dg_d + N);           // 128*128
    ushort* Wt_d = Wt_c + 16384;                  // 256*256
    int* dbuf_c = (int*)(Wt_d + 65536);           // NBKT*capc
    int* sbuf_c = dbuf_c + (size_t)NBKT * capc;   // NBKT*capc
    int* dbuf_d = sbuf_c + (size_t)NBKT * capc;   // NBKT*capd
    int* sbuf_d = dbuf_d + (size_t)NBKT * capd;   // NBKT*capd
    ushort* Xb_c = (ushort*)(sbuf_d + (size_t)NBKT * capd);  // N*128
    ushort* Xb_d = Xb_c + (size_t)N * D_c;        // N*256

    hipMemsetAsync(gf_cd, 0, 1024 * sizeof(int), stream);

    wprep_kernel<<<40, 256, 0, stream>>>(W_c, W_d, Wt_c, Wt_d);

    const int Rc = (E_c + RND - 1) / RND;
    const int Rd = (E_d + RND - 1) / RND;
    part_kernel<<<2 * (Rc + Rd), 256, 0, stream>>>(
        src_c, dst_c, E_c, Rc, src_d, dst_d, E_d, Rd,
        gf_cd, gf_cs, gf_dd, gf_ds,
        dbuf_c, sbuf_c, dbuf_d, sbuf_d, capc, capd);

    b2s_kernel<<<2 * NBKT, 256, 0, stream>>>(
        sbuf_c, gf_cs, capc, cnt_out_c,
        sbuf_d, gf_ds, capd, cnt_out_d, N, NBKT);

    int nbc = (N * (D_c / 4) + 255) / 256, nbd = (N * (D_d / 4) + 255) / 256;
    cast_kernel<<<nbc + nbd, 256, 0, stream>>>(feat_c, cnt_out_c, Xb_c,
                                               feat_d, cnt_out_d, Xb_d, N, nbc);

    b2d_kernel<<<2 * NBKT, 256, 0, stream>>>(
        dbuf_c, gf_cd, capc, rs_c, dg_c,
        dbuf_d, gf_dd, capd, rs_d, dg_d, N, NBKT);

    const int nblk = (N + 31) / 32;
    fused_kernel<<<2 * nblk, 512, 0, stream>>>(
        Xb_c, rs_c, dg_c, dbuf_c, Wt_c, b_c, out_c,
        Xb_d, rs_d, dg_d, dbuf_d, Wt_d, b_d, out_d, N, nblk);
}

// Round 7
// 402.702 us; speedup vs baseline: 1.0997x; 1.0997x over previous
//
#include <hip/hip_runtime.h>
#include <hip/hip_bf16.h>

// ---------------------------------------------------------------------------
// GraphConv (DGL, norm='both', relu) x2, aggregate-first:
//   out = relu( (D_in^-1/2 A D_out^-1/2 X) @ W + b )
// Pipeline:
//   memset : 4 bucket-cursor arrays (4KB)
//   wprep  : W -> bf16 W^T image as [128n x 64k] XOR-swizzled 16KB tiles
//            (c: 2 tiles (K=128); d: 2 col-halves x 4 k-chunks = 8 tiles)
//   part   : edges -> 196 coarse buckets, 4 channels (c/d x dst/src),
//            in-LDS chunk sort + run-coalesced flush (write-combined)
//   b2s    : per src-bucket 256-bin LDS count -> out-degree
//   cast   : Xb = bf16(X * rsqrt(outdeg))
//   b2d    : per dst-bucket LDS sort -> linear CSR + rs/deg
//   fused  : per block (512 thr): 8 waves gather 32 nodes -> bf16 LDS a-tile
//            -> MFMA over 16KB W tiles (global_load_lds) -> bias+relu -> out.
//            LDS 32KB total => 4 blocks/CU (occupancy fix vs 48KB round 6).
// ---------------------------------------------------------------------------

typedef __attribute__((ext_vector_type(8))) short short8;
typedef __attribute__((ext_vector_type(4))) float f32x4;

#define RND 4096      // edges per partition chunk
#define CAPMAX 8960   // max bucket capacity (LDS sort limit)

static __device__ __forceinline__ ushort f2b(float f) {
    __hip_bfloat16 h = __float2bfloat16(f);
    return *reinterpret_cast<ushort*>(&h);
}
static __device__ __forceinline__ float b2f(ushort u) {
    union { unsigned int i; float f; } c;
    c.i = ((unsigned int)u) << 16;
    return c.f;
}
static __device__ __forceinline__ void gld_lds16(const void* g, void* l) {
    __builtin_amdgcn_global_load_lds(
        (const __attribute__((address_space(1))) unsigned int*)g,
        (__attribute__((address_space(3))) unsigned int*)l, 16, 0, 0);
}

// ---------------- part: 4-channel chunk partition with WC flush ------------
__global__ __launch_bounds__(256) void part_kernel(
    const int* __restrict__ src_c, const int* __restrict__ dst_c, int Ec, int Rc,
    const int* __restrict__ src_d, const int* __restrict__ dst_d, int Ed, int Rd,
    int* gf_cd, int* gf_cs, int* gf_dd, int* gf_ds,
    int* dbuf_c, int* sbuf_c, int* dbuf_d, int* sbuf_d, int capc, int capd)
{
    __shared__ int pk[RND];
    __shared__ unsigned char pb[RND];
    __shared__ int hist[256], st[256], ex2[256], cur[256], gbase[256];

    const int tid = threadIdx.x;
    const int bid = blockIdx.x;
    const int* keys; const int* pays; int E; int* gf; int* buf; int cap; int e0;
    if (bid < Rc)            { keys = dst_c; pays = src_c; E = Ec; gf = gf_cd; buf = dbuf_c; cap = capc; e0 = bid * RND; }
    else if (bid < 2 * Rc)   { keys = src_c; pays = 0;     E = Ec; gf = gf_cs; buf = sbuf_c; cap = capc; e0 = (bid - Rc) * RND; }
    else if (bid < 2 * Rc + Rd) { keys = dst_d; pays = src_d; E = Ed; gf = gf_dd; buf = dbuf_d; cap = capd; e0 = (bid - 2 * Rc) * RND; }
    else                     { keys = src_d; pays = 0;     E = Ed; gf = gf_ds; buf = sbuf_d; cap = capd; e0 = (bid - 2 * Rc - Rd) * RND; }

    hist[tid] = 0;
    __syncthreads();

    int kb[RND / 256], pv[RND / 256];
    int n = 0;
#pragma unroll
    for (int r = 0; r < RND / 256; ++r) {
        int e = e0 + r * 256 + tid;
        if (e < E) {
            int k = keys[e];
            pv[r] = pays ? ((pays[e] << 8) | (k & 255)) : k;
            kb[r] = k >> 8;
            atomicAdd(&hist[kb[r]], 1);
            n = r + 1;
        }
    }
    __syncthreads();

    int x = hist[tid];
    st[tid] = x;
    __syncthreads();
    for (int off = 1; off < 256; off <<= 1) {
        int t2 = 0;
        if (tid >= off) t2 = st[tid - off];
        __syncthreads();
        if (tid >= off) st[tid] += t2;
        __syncthreads();
    }
    ex2[tid] = st[tid] - x;
    cur[tid] = st[tid] - x;
    __syncthreads();

    for (int r = 0; r < n; ++r) {
        int slot = atomicAdd(&cur[kb[r]], 1);
        pk[slot] = pv[r];
        pb[slot] = (unsigned char)kb[r];
    }
    if (x) gbase[tid] = atomicAdd(&gf[tid], x);
    __syncthreads();

    int m = st[255];
    for (int i = tid; i < m; i += 256) {
        int b = pb[i];
        int pos = gbase[b] + (i - ex2[b]);
        if (pos < cap) buf[(size_t)b * cap + pos] = pk[i];
    }
}

// ---------------- b2s: per src-bucket count -> out-degree ------------------
__global__ __launch_bounds__(256) void b2s_kernel(
    const int* __restrict__ sbuf_c, const int* __restrict__ gf_cs, int capc, int* cnt_c,
    const int* __restrict__ sbuf_d, const int* __restrict__ gf_ds, int capd, int* cnt_d,
    int N, int NBKT)
{
    __shared__ int h[256];
    const int tid = threadIdx.x;
    const int* sbuf; const int* gf; int cap; int* cnt; int bb;
    if ((int)blockIdx.x < NBKT) { sbuf = sbuf_c; gf = gf_cs; cap = capc; cnt = cnt_c; bb = blockIdx.x; }
    else { sbuf = sbuf_d; gf = gf_ds; cap = capd; cnt = cnt_d; bb = blockIdx.x - NBKT; }
    h[tid] = 0;
    __syncthreads();
    int m = gf[bb]; if (m > cap) m = cap;
    const int* reg = sbuf + (size_t)bb * cap;
    for (int i = tid; i < m; i += 256) atomicAdd(&h[reg[i] & 255], 1);
    __syncthreads();
    int v = bb * 256 + tid;
    if (v < N) cnt[v] = h[tid];
}

// ---------------- b2d: per dst-bucket LDS sort -> linear CSR + rs/deg ------
__global__ __launch_bounds__(256) void b2d_kernel(
    int* dbuf_c, const int* __restrict__ gf_cd, int capc, int* rs_c, int* dg_c,
    int* dbuf_d, const int* __restrict__ gf_dd, int capd, int* rs_d, int* dg_d,
    int N, int NBKT)
{
    __shared__ int pk[CAPMAX];
    __shared__ int h[256], st[256], ex2[256], cur[256];
    const int tid = threadIdx.x;
    int* bbuf; const int* gf; int cap; int* rs; int* dg; int bb;
    if ((int)blockIdx.x < NBKT) { bbuf = dbuf_c; gf = gf_cd; cap = capc; rs = rs_c; dg = dg_c; bb = blockIdx.x; }
    else { bbuf = dbuf_d; gf = gf_dd; cap = capd; rs = rs_d; dg = dg_d; bb = blockIdx.x - NBKT; }

    int m = gf[bb]; if (m > cap) m = cap;
    int* reg = bbuf + (size_t)bb * cap;

    h[tid] = 0;
    __syncthreads();
    for (int i = tid; i < m; i += 256) atomicAdd(&h[reg[i] & 255], 1);
    __syncthreads();
    int x = h[tid];
    st[tid] = x;
    __syncthreads();
    for (int off = 1; off < 256; off <<= 1) {
        int t2 = 0;
        if (tid >= off) t2 = st[tid - off];
        __syncthreads();
        if (tid >= off) st[tid] += t2;
        __syncthreads();
    }
    int ex_t = st[tid] - x;
    ex2[tid] = ex_t;
    cur[tid] = ex_t;
    int v = bb * 256 + tid;
    if (v < N) { rs[v] = bb * cap + ex_t; dg[v] = x; }
    __syncthreads();
    for (int i = tid; i < m; i += 256) {
        int p = reg[i];
        int slot = atomicAdd(&cur[p & 255], 1);
        pk[slot] = p >> 8;
    }
    __syncthreads();
    for (int i = tid; i < m; i += 256) reg[i] = pk[i];
}

// ---------------- W prep: uniform [128n x 64k] swizzled 16KB tiles ---------
// tile index t = ch*4 + ci (c: ch=0, t=ci in {0,1}); within tile:
//   Wt[t*8192 + np*64 + slot*8 + j] = W[ci*64 + ((slot^(np&7))<<3) + j][ch*128+np]
__global__ __launch_bounds__(256) void wprep_kernel(
    const float* __restrict__ Wc, const float* __restrict__ Wd,
    ushort* __restrict__ Wtc, ushort* __restrict__ Wtd)
{
    int t = blockIdx.x * 256 + threadIdx.x;
    const float* W; ushort* Wt; int BN, tile, idx;
    if (t < 2048)        { W = Wc; Wt = Wtc; BN = 128; tile = t >> 10; idx = t & 1023; }
    else if (t < 10240)  { int tt = t - 2048; W = Wd; Wt = Wtd; BN = 256; tile = tt >> 10; idx = tt & 1023; }
    else return;
    int np = idx >> 3, slot = idx & 7;
    int ch = tile >> 2, ci = tile & 3;
    int k0 = ci * 64 + ((slot ^ (np & 7)) << 3);
    int ncol = ch * 128 + np;
    ushort o[8];
#pragma unroll
    for (int j = 0; j < 8; ++j) o[j] = f2b(W[(size_t)(k0 + j) * BN + ncol]);
    uint4 vv;
    vv.x = (unsigned)o[0] | ((unsigned)o[1] << 16);
    vv.y = (unsigned)o[2] | ((unsigned)o[3] << 16);
    vv.z = (unsigned)o[4] | ((unsigned)o[5] << 16);
    vv.w = (unsigned)o[6] | ((unsigned)o[7] << 16);
    *(uint4*)&Wt[tile * 8192 + np * 64 + slot * 8] = vv;
}

// ---------------- cast + out-norm scale to bf16 ----------------------------
__global__ __launch_bounds__(256) void cast_kernel(
    const float* __restrict__ Xc, const int* __restrict__ coc, ushort* __restrict__ Xbc,
    const float* __restrict__ Xd, const int* __restrict__ cod, ushort* __restrict__ Xbd,
    int N, int nbc)
{
    const float* X; const int* co; ushort* Xb; int C4, t;
    if ((int)blockIdx.x < nbc) { X = Xc; co = coc; Xb = Xbc; C4 = 32; t = blockIdx.x * 256 + threadIdx.x; }
    else { X = Xd; co = cod; Xb = Xbd; C4 = 64; t = (blockIdx.x - nbc) * 256 + threadIdx.x; }
    if (t >= N * C4) return;
    int row = t / C4, c4 = t % C4;
    int od = co[row]; if (od < 1) od = 1;
    float nr = rsqrtf((float)od);
    float4 xv = ((const float4*)(X + (size_t)row * (C4 * 4)))[c4];
    ushort4 o;
    o.x = f2b(xv.x * nr); o.y = f2b(xv.y * nr);
    o.z = f2b(xv.z * nr); o.w = f2b(xv.w * nr);
    ((ushort4*)(Xb + (size_t)row * (C4 * 4)))[c4] = o;
}

// ---------------- fused gather + MFMA GEMM + bias + relu -------------------
// Block: 512 threads (8 waves), 32 dst nodes.
// LDS: At (<=16KB) + 16KB W tile = 32KB -> 4 blocks/CU.
template <int VEC>   // 2: D=128 (graph c), 4: D=256 (graph d)
static __device__ __forceinline__ void fused_branch(
    int blk, const ushort* __restrict__ Xb, const int* __restrict__ rs,
    const int* __restrict__ dg, const int* __restrict__ csr,
    const ushort* __restrict__ Wt, const float* __restrict__ bias,
    float* __restrict__ out, int N, ushort* At, ushort* Wls)
{
    constexpr int D = VEC * 64;
    constexpr int CH = VEC / 2;       // col-halves of 128: c=1, d=2
    constexpr int KCH = VEC;          // 64-wide k-chunks: c=2, d=4
    const int tid = threadIdx.x;
    const int lane = tid & 63, wid = tid >> 6;

    // stage W tile 0 early — hides under gather latency (16KB = 2x512x16B)
#pragma unroll
    for (int it = 0; it < 2; ++it) {
        int off16 = it * 512 + tid;
        gld_lds16(&Wt[off16 * 8], &Wls[off16 * 8]);
    }

    // ---- gather: 8 waves x 4 nodes ----
    const int node0 = blk * 32;
#pragma unroll
    for (int s = 0; s < 4; ++s) {
        const int row = wid * 4 + s;
        const int v = node0 + row;
        float acc[VEC];
#pragma unroll
        for (int k = 0; k < VEC; ++k) acc[k] = 0.f;
        int deg = 0;
        if (v < N) {
            deg = dg[v];
            const int* rowp = csr + rs[v];
            for (int base = 0; base < deg; base += 64) {
                int m = deg - base; if (m > 64) m = 64;
                int u_l = (lane < m) ? rowp[base + lane] : 0;
#pragma unroll 8
                for (int j = 0; j < m; ++j) {
                    int u = __shfl(u_l, j);
                    const ushort* xr = Xb + (size_t)u * D + lane * VEC;
                    if constexpr (VEC == 2) {
                        unsigned int xv = *(const unsigned int*)xr;
                        acc[0] += b2f((ushort)(xv & 0xffff));
                        acc[1] += b2f((ushort)(xv >> 16));
                    } else {
                        uint2 xv = *(const uint2*)xr;
                        acc[0] += b2f((ushort)(xv.x & 0xffff));
                        acc[1] += b2f((ushort)(xv.x >> 16));
                        acc[2] += b2f((ushort)(xv.y & 0xffff));
                        acc[3] += b2f((ushort)(xv.y >> 16));
                    }
                }
            }
        }
        // emit bf16 row (zeros for v>=N), XOR-swizzled slot layout
        float nd = rsqrtf((float)(deg < 1 ? 1 : deg));
        const int k0 = lane * VEC;
        const int slot = (k0 >> 3) ^ (row & 7);
        ushort* dstp = &At[row * D + slot * 8 + (k0 & 7)];
        if constexpr (VEC == 2) {
            unsigned int pk = (unsigned)f2b(acc[0] * nd) | ((unsigned)f2b(acc[1] * nd) << 16);
            *(unsigned int*)dstp = pk;
        } else {
            uint2 pk;
            pk.x = (unsigned)f2b(acc[0] * nd) | ((unsigned)f2b(acc[1] * nd) << 16);
            pk.y = (unsigned)f2b(acc[2] * nd) | ((unsigned)f2b(acc[3] * nd) << 16);
            *(uint2*)dstp = pk;
        }
    }
    __syncthreads();   // a-tile ready; W tile 0 drained (vmcnt before barrier)

    // ---- MFMA: waves 2(row-tiles of 16) x 4(col-groups of 32 within half) --
    const int wr = wid >> 2, wc = wid & 3;
    const int lr = lane & 15, lk8 = (lane >> 4) * 8;
    f32x4 acc[CH][2];
#pragma unroll
    for (int ch = 0; ch < CH; ++ch)
#pragma unroll
        for (int nc = 0; nc < 2; ++nc) acc[ch][nc] = (f32x4)0.f;

#pragma unroll
    for (int ch = 0; ch < CH; ++ch) {
#pragma unroll
        for (int ci = 0; ci < KCH; ++ci) {
            const int tile = ch * KCH + ci;
            if (tile) {
                __syncthreads();   // prior MFMA reads of Wls done
#pragma unroll
                for (int it = 0; it < 2; ++it) {
                    int off16 = it * 512 + tid;
                    gld_lds16(&Wt[tile * 8192 + off16 * 8], &Wls[off16 * 8]);
                }
                __syncthreads();
            }
#pragma unroll
            for (int k0 = 0; k0 < 64; k0 += 32) {
                const int r = wr * 16 + lr;
                const int kg = ci * 64 + k0 + lk8;
                const int aslot = (kg >> 3) ^ (r & 7);
                short8 a = *(const short8*)&At[r * D + aslot * 8];
#pragma unroll
                for (int nc = 0; nc < 2; ++nc) {
                    const int np = wc * 32 + nc * 16 + lr;
                    const int kk = k0 + lk8;
                    const int bslot = (kk >> 3) ^ (np & 7);
                    short8 b = *(const short8*)&Wls[np * 64 + bslot * 8];
                    acc[ch][nc] = __builtin_amdgcn_mfma_f32_16x16x32_bf16(a, b, acc[ch][nc], 0, 0, 0);
                }
            }
        }
    }

    // epilogue: bias + relu (C/D: col=lane&15, row=(lane>>4)*4+reg)
#pragma unroll
    for (int ch = 0; ch < CH; ++ch)
#pragma unroll
        for (int nc = 0; nc < 2; ++nc) {
            const int col = ch * 128 + wc * 32 + nc * 16 + lr;
            const float bv = bias[col];
#pragma unroll
            for (int r4 = 0; r4 < 4; ++r4) {
                const int row = wr * 16 + (lane >> 4) * 4 + r4;
                const int v = node0 + row;
                if (v < N)
                    out[(size_t)v * D + col] = fmaxf(acc[ch][nc][r4] + bv, 0.f);
            }
        }
}

__global__ __launch_bounds__(512) void fused_kernel(
    const ushort* __restrict__ Xbc, const int* __restrict__ rsc,
    const int* __restrict__ dgc, const int* __restrict__ csrc,
    const ushort* __restrict__ Wtc, const float* __restrict__ bc, float* outc,
    const ushort* __restrict__ Xbd, const int* __restrict__ rsd,
    const int* __restrict__ dgd, const int* __restrict__ csrd,
    const ushort* __restrict__ Wtd, const float* __restrict__ bd, float* outd,
    int N, int nblkc)
{
    __shared__ ushort At[32 * 256];   // 16 KB (c uses first 8 KB)
    __shared__ ushort Wls[8192];      // 16 KB W tile
    if ((int)blockIdx.x < nblkc)
        fused_branch<2>(blockIdx.x, Xbc, rsc, dgc, csrc, Wtc, bc, outc, N, At, Wls);
    else
        fused_branch<4>(blockIdx.x - nblkc, Xbd, rsd, dgd, csrd, Wtd, bd, outd, N, At, Wls);
}

// ---------------------------------------------------------------------------
extern "C" void kernel_launch(void* const* d_in, const int* in_sizes, int n_in,
                              void* d_out, int out_size, void* d_ws, size_t ws_size,
                              hipStream_t stream)
{
    const float* feat_c = (const float*)d_in[0];
    const float* feat_d = (const float*)d_in[1];
    const int* src_c = (const int*)d_in[2];
    const int* dst_c = (const int*)d_in[3];
    const int* src_d = (const int*)d_in[4];
    const int* dst_d = (const int*)d_in[5];
    const float* W_c = (const float*)d_in[6];
    const float* b_c = (const float*)d_in[7];
    const float* W_d = (const float*)d_in[8];
    const float* b_d = (const float*)d_in[9];

    const int D_c = in_sizes[7];          // 128
    const int D_d = in_sizes[9];          // 256
    const int N = in_sizes[0] / D_c;      // 50000
    const int E_c = in_sizes[2];
    const int E_d = in_sizes[4];

    float* out_c = (float*)d_out;
    float* out_d = (float*)d_out + (size_t)N * D_c;

    const int NBKT = (N + 255) >> 8;      // 196
    int capc = E_c / NBKT; capc += 8 * (int)sqrtf((float)capc) + 32; capc = (capc + 15) & ~15;
    int capd = E_d / NBKT; capd += 8 * (int)sqrtf((float)capd) + 32; capd = (capd + 15) & ~15;
    if (capc > CAPMAX) capc = CAPMAX;
    if (capd > CAPMAX) capd = CAPMAX;

    // workspace layout (ints unless noted)
    int* ws = (int*)d_ws;
    int* cnt_out_c = ws;                          // N
    int* cnt_out_d = ws + N;                      // N
    int* gf_cd = ws + 2 * (size_t)N;              // 256
    int* gf_cs = gf_cd + 256;                     // 256
    int* gf_dd = gf_cs + 256;                     // 256
    int* gf_ds = gf_dd + 256;                     // 256
    int* rs_c  = gf_ds + 256;                     // N
    int* dg_c  = rs_c + N;                        // N
    int* rs_d  = dg_c + N;                        // N
    int* dg_d  = rs_d + N;                        // N
    ushort* Wt_c = (ushort*)(dg_d + N);           // 2 tiles  * 8192
    ushort* Wt_d = Wt_c + 16384;                  // 8 tiles  * 8192
    int* dbuf_c = (int*)(Wt_d + 65536);           // NBKT*capc
    int* sbuf_c = dbuf_c + (size_t)NBKT * capc;   // NBKT*capc
    int* dbuf_d = sbuf_c + (size_t)NBKT * capc;   // NBKT*capd
    int* sbuf_d = dbuf_d + (size_t)NBKT * capd;   // NBKT*capd
    ushort* Xb_c = (ushort*)(sbuf_d + (size_t)NBKT * capd);  // N*128
    ushort* Xb_d = Xb_c + (size_t)N * D_c;        // N*256

    hipMemsetAsync(gf_cd, 0, 1024 * sizeof(int), stream);

    wprep_kernel<<<40, 256, 0, stream>>>(W_c, W_d, Wt_c, Wt_d);

    const int Rc = (E_c + RND - 1) / RND;
    const int Rd = (E_d + RND - 1) / RND;
    part_kernel<<<2 * (Rc + Rd), 256, 0, stream>>>(
        src_c, dst_c, E_c, Rc, src_d, dst_d, E_d, Rd,
        gf_cd, gf_cs, gf_dd, gf_ds,
        dbuf_c, sbuf_c, dbuf_d, sbuf_d, capc, capd);

    b2s_kernel<<<2 * NBKT, 256, 0, stream>>>(
        sbuf_c, gf_cs, capc, cnt_out_c,
        sbuf_d, gf_ds, capd, cnt_out_d, N, NBKT);

    int nbc = (N * (D_c / 4) + 255) / 256, nbd = (N * (D_d / 4) + 255) / 256;
    cast_kernel<<<nbc + nbd, 256, 0, stream>>>(feat_c, cnt_out_c, Xb_c,
                                               feat_d, cnt_out_d, Xb_d, N, nbc);

    b2d_kernel<<<2 * NBKT, 256, 0, stream>>>(
        dbuf_c, gf_cd, capc, rs_c, dg_c,
        dbuf_d, gf_dd, capd, rs_d, dg_d, N, NBKT);

    const int nblk = (N + 31) / 32;
    fused_kernel<<<2 * nblk, 512, 0, stream>>>(
        Xb_c, rs_c, dg_c, dbuf_c, Wt_c, b_c, out_c,
        Xb_d, rs_d, dg_d, dbuf_d, Wt_d, b_d, out_d, N, nblk);
}